// Round 1
// baseline (180.018 us; speedup 1.0000x reference)
//
#include <hip/hip_runtime.h>
#include <hip/hip_cooperative_groups.h>
#include <math.h>

#define NS2 0.70710678118654752440f  // 1/sqrt(2)
#define NS3 0.57735026918962576451f  // 1/sqrt(3)
#define NS6 0.40824829046386301636f  // 1/sqrt(6)

typedef _Float16 f16;
typedef _Float16 f16x8 __attribute__((ext_vector_type(8)));
typedef float    f32x4 __attribute__((ext_vector_type(4)));

#define GT_K    22528
#define UV_ROW  216
#define OFF_UV  157696   // 7*22528

namespace cg = cooperative_groups;

// ---------------------------------------------------------------------------
// Phase A part 1: G_T build. 4 o-split threads per k (q = tid>>6), kl = tid&63,
// handles k = k_base + kl for kl < n_k. LDS: s_wo[1680] + s_red[4][64][8].
// ---------------------------------------------------------------------------
__device__ __forceinline__ void build_gt(
    const float* __restrict__ W3_0, const float* __restrict__ W3_1,
    const float* __restrict__ W3_2, const float* __restrict__ Wout,
    f16* __restrict__ wsh, float* smem, int k_base, int n_k)
{
    const int tid = threadIdx.x;
    float* s_wo  = smem;            // Wout 240x7
    float* s_red = smem + 1680;     // [4][64][8] partials
    for (int i = tid; i < 1680; i += 256) s_wo[i] = Wout[i];
    __syncthreads();
    const int kl = tid & 63, q = tid >> 6;
    if (kl < n_k) {
        const int k = k_base + kl;
        float acc[7] = {0.f,0.f,0.f,0.f,0.f,0.f,0.f};
        if (k < 4096) {                            // P1  (L=64, quarter=16)
            const float* wr = W3_0 + (size_t)k * 64;
            #pragma unroll
            for (int oo = 0; oo < 16; oo += 4) {
                int o = q*16 + oo;
                float4 wv = *(const float4*)(wr + o);
                const float* w0 = s_wo + o * 7;
                #pragma unroll
                for (int kk = 0; kk < 7; ++kk)
                    acc[kk] = fmaf(wv.x, w0[kk], fmaf(wv.y, w0[7+kk],
                              fmaf(wv.z, w0[14+kk], fmaf(wv.w, w0[21+kk], acc[kk]))));
            }
        } else if (k < 10240) {                    // P4  (L=32, quarter=8)
            int it = k >> 6, s = it - 64, m = s >> 5, a2 = s & 31, l = k & 63;
            const float* wr = W3_1 + (size_t)(2048 + a2*64 + l) * 32;
            #pragma unroll
            for (int oo = 0; oo < 8; oo += 4) {
                int o = q*8 + oo;
                float4 wv = *(const float4*)(wr + o);
                const float* w0 = s_wo + (64 + o*3 + m) * 7;
                #pragma unroll
                for (int kk = 0; kk < 7; ++kk)
                    acc[kk] = fmaf(wv.x, w0[kk], fmaf(wv.y, w0[21+kk],
                              fmaf(wv.z, w0[42+kk], fmaf(wv.w, w0[63+kk], acc[kk]))));
            }
        } else {
            int it2 = (k - 10240) >> 5, l32 = k & 31;
            if (it2 < 32) {                        // P2  (L=64)
                const float* wr = W3_0 + (size_t)(4096 + it2*32 + l32) * 64;
                #pragma unroll
                for (int oo = 0; oo < 16; oo += 4) {
                    int o = q*16 + oo;
                    float4 wv = *(const float4*)(wr + o);
                    const float* w0 = s_wo + o * 7;
                    #pragma unroll
                    for (int kk = 0; kk < 7; ++kk)
                        acc[kk] = fmaf(wv.x, w0[kk], fmaf(wv.y, w0[7+kk],
                                  fmaf(wv.z, w0[14+kk], fmaf(wv.w, w0[21+kk], acc[kk]))));
                }
            } else if (it2 < 224) {                // P3  (L=32)
                int t = it2 - 32, m = t >> 6, a = t & 63;
                const float* wr = W3_1 + (size_t)(a*32 + l32) * 32;
                #pragma unroll
                for (int oo = 0; oo < 8; oo += 4) {
                    int o = q*8 + oo;
                    float4 wv = *(const float4*)(wr + o);
                    const float* w0 = s_wo + (64 + o*3 + m) * 7;
                    #pragma unroll
                    for (int kk = 0; kk < 7; ++kk)
                        acc[kk] = fmaf(wv.x, w0[kk], fmaf(wv.y, w0[21+kk],
                                  fmaf(wv.z, w0[42+kk], fmaf(wv.w, w0[63+kk], acc[kk]))));
                }
            } else {                               // P5  (L=16, quarter=4)
                int t = it2 - 224, m = t >> 5, a = t & 31;
                const float* wr = W3_2 + (size_t)(a*32 + l32) * 16;
                int o = q*4;
                float4 wv = *(const float4*)(wr + o);
                const float* w0 = s_wo + (160 + o*5 + m) * 7;
                #pragma unroll
                for (int kk = 0; kk < 7; ++kk)
                    acc[kk] = fmaf(wv.x, w0[kk], fmaf(wv.y, w0[35+kk],
                              fmaf(wv.z, w0[70+kk], fmaf(wv.w, w0[105+kk], acc[kk]))));
            }
        }
        #pragma unroll
        for (int r = 0; r < 7; ++r) s_red[(q*64 + kl)*8 + r] = acc[r];
    }
    __syncthreads();
    if (tid < n_k) {
        #pragma unroll
        for (int r = 0; r < 7; ++r) {
            float v = s_red[(      tid)*8 + r] + s_red[( 64 + tid)*8 + r]
                    + s_red[(128 + tid)*8 + r] + s_red[(192 + tid)*8 + r];
            wsh[(size_t)r * GT_K + k_base + tid] = (f16)v;
        }
    }
}

// ---------------------------------------------------------------------------
// Phase A part 2: per-node features for 8 nodes starting at `base`.
// LDS: s_f0[8][64] + s_f1[8][32] (overlays build_gt's s_wo region — s_wo is
// only read before build_gt's 2nd barrier, and s_red is disjoint, so this is
// race-free even when called right after build_gt).
// ---------------------------------------------------------------------------
__device__ __forceinline__ void build_nodes(
    const float* __restrict__ pos,
    const float* __restrict__ W1_0, const float* __restrict__ W1_1,
    const float* __restrict__ W2_0, const float* __restrict__ W2_1,
    const float* __restrict__ bout,
    f16* __restrict__ wsh, float* __restrict__ out, float* smem, int base)
{
    const int tid = threadIdx.x;
    float* s_f0 = smem;          // [8][64]
    float* s_f1 = smem + 512;    // [8][32]
    f16* uv = wsh + OFF_UV;
    {
        int d = tid & 63;
        #pragma unroll
        for (int jj = 0; jj < 2; ++jj) {
            int j = (tid >> 6) + jj * 4;
            int n = base + j;
            float px = pos[n*3+0], py = pos[n*3+1], pz = pos[n*3+2];
            float r  = sqrtf(px*px + py*py + pz*pz) + 1e-9f;
            float t0 = r - (5.0f/63.0f) * (float)d;
            s_f0[j*64 + d] = __expf(-4.f * t0 * t0);
        }
        {
            int j = tid >> 5, d1 = tid & 31;
            int n = base + j;
            float px = pos[n*3+0], py = pos[n*3+1], pz = pos[n*3+2];
            float r  = sqrtf(px*px + py*py + pz*pz) + 1e-9f;
            float t1 = r - (5.0f/31.0f) * (float)d1;
            s_f1[j*32 + d1] = __expf(-4.f * t1 * t1);
        }
        if (tid < 8) {
            int n = base + tid;
            float px = pos[n*3+0], py = pos[n*3+1], pz = pos[n*3+2];
            float r  = sqrtf(px*px + py*py + pz*pz) + 1e-9f;
            float iv = 1.0f / r;
            float d0 = py*iv, d1 = pz*iv, d2 = px*iv;       // (y,z,x)
            f16* row = uv + (size_t)n * UV_ROW;
            row[192+0] = (f16)d0;
            row[192+1] = (f16)d1;
            row[192+2] = (f16)d2;
            row[192+3] = (f16)(NS3 * (d0*d0 + d1*d1 + d2*d2));
            row[192+4] = (f16)(2.f*NS2*d2*d0);
            row[192+5] = (f16)(2.f*NS2*d0*d1);
            row[192+6] = (f16)(NS6*(2.f*d1*d1 - d2*d2 - d0*d0));
            row[192+7] = (f16)(2.f*NS2*d2*d1);
            row[192+8] = (f16)(NS2*(d2*d2 - d0*d0));
            row[201]   = (f16)1.0f;
        }
        if (tid < 56) out[base*7 + tid] = bout[tid % 7];
    }
    __syncthreads();
    {
        int c = tid & 63, jb = tid >> 6;
        float aa0 = 0.f, aa1 = 0.f, ba0 = 0.f, ba1 = 0.f;
        const float* wa = W1_0 + c;
        const float* wb = W2_0 + c;
        #pragma unroll 4
        for (int d = 0; d < 64; ++d) {
            float wav = wa[d*64], wbv = wb[d*64];
            float fA = s_f0[jb*64 + d], fB = s_f0[(jb+4)*64 + d];
            aa0 = fmaf(fA, wav, aa0);  aa1 = fmaf(fB, wav, aa1);
            ba0 = fmaf(fA, wbv, ba0);  ba1 = fmaf(fB, wbv, ba1);
        }
        uv[(size_t)(base+jb  )*UV_ROW +      c] = (f16)aa0;
        uv[(size_t)(base+jb+4)*UV_ROW +      c] = (f16)aa1;
        uv[(size_t)(base+jb  )*UV_ROW + 96 + c] = (f16)ba0;
        uv[(size_t)(base+jb+4)*UV_ROW + 96 + c] = (f16)ba1;

        int c1 = tid & 31, j8 = tid >> 5;
        float aA = 0.f, aB = 0.f;
        const float* wA = W1_1 + c1;
        const float* wB = W2_1 + c1;
        #pragma unroll 4
        for (int d = 0; d < 32; ++d) {
            float f = s_f1[j8*32 + d];
            aA = fmaf(f, wA[d*32], aA);
            aB = fmaf(f, wB[d*32], aB);
        }
        uv[(size_t)(base+j8)*UV_ROW +  64 + c1] = (f16)aA;
        uv[(size_t)(base+j8)*UV_ROW + 160 + c1] = (f16)aB;
    }
}

// ---------------------------------------------------------------------------
// Phase B: D = G_T(16 x K_eighth) x z(K_eighth x 16 nodes) per wave.
// LDS layout inside smem_raw (39552 B):
//   [0]      s_g[2][8][264]  f16   (8448 B)   G_T tile, row 7 zeroed
//   [8448]   s_uv[64][216]   f16   (27648 B)  per-node u/v/geom
//   [36096]  s_ugt[2][64][8] f16   (2048 B)   u*geom per (node, chunk)
//   [38144]  s_idx[704]      u16   (1408 B)
// Tile loop uses async-stage split: issue G_T load -> ugt LDS work ->
// MFMA compute(current buf) -> ds_write staged regs (vmcnt wait lands here).
// ---------------------------------------------------------------------------
__device__ __forceinline__ void phaseB(const f16* __restrict__ wsh,
                                       float* __restrict__ out,
                                       char* smem_raw, int g, int kq)
{
    f16 (*s_g)[8][264]   = (f16(*)[8][264])(smem_raw);
    f16 (*s_uv)[UV_ROW]  = (f16(*)[UV_ROW])(smem_raw + 8448);
    f16 (*s_ugt)[64][8]  = (f16(*)[64][8])(smem_raw + 8448 + 27648);
    unsigned short* s_idx = (unsigned short*)(smem_raw + 8448 + 27648 + 2048);

    const int tid  = threadIdx.x;
    const int w    = tid >> 6;
    const int lane = tid & 63;
    const int lq   = lane >> 4;            // quad: A/B k-subrange, D row-group
    const int lm   = lane & 15;            // A row (out-k) / B col (node) / D col
    const int ra   = (lm < 7) ? lm : 7;    // A-source row (7 = zero row)

    // ---- stage per-node table; idx table; zero row 7 of both G bufs ----
    {
        const uint4* src = (const uint4*)(wsh + OFF_UV + (size_t)g * 64 * UV_ROW);
        uint4* dst = (uint4*)&s_uv[0][0];
        for (int j = tid; j < 1728; j += 256) dst[j] = src[j];
        for (int c = tid; c < 704; c += 256) {
            int uidx, gidx;
            if (c < 320) {
                int it = c >> 1;
                if (it < 64) { uidx = it; gidx = 9; }
                else { int s = it - 64; uidx = 64 + (s & 31); gidx = s >> 5; }
            } else {
                int it2 = c - 320;
                if (it2 < 32)       { uidx = 64 + it2;                 gidx = 3; }
                else if (it2 < 224) { int t = it2 - 32;  uidx = t & 63;        gidx = t >> 6; }
                else                { int t = it2 - 224; uidx = 64 + (t & 31); gidx = 4 + (t >> 5); }
            }
            s_idx[c] = (unsigned short)(uidx | (gidx << 8));
        }
        for (int i = tid; i < 264; i += 256) {
            s_g[0][7][i] = (f16)0.f;
            s_g[1][7][i] = (f16)0.f;
        }
    }
    __syncthreads();

    // ---- per-lane constant v-fragments ----
    const f16* myrow = &s_uv[w*16 + lm][0];
    f16x8 vA0 = *(const f16x8*)(myrow +  96 + lq*8);   // b0[ 0..31] slice
    f16x8 vA1 = *(const f16x8*)(myrow + 128 + lq*8);   // b0[32..63] slice
    f16x8 vB  = *(const f16x8*)(myrow + 160 + lq*8);   // B1[ 0..31] slice

    auto c0_of = [&](int t) {
        return (t < 5) ? (kq*40 + t*8) : (320 + kq*48 + (t-5)*8);
    };

    const int  srow  = tid >> 5, scol = tid & 31;
    const bool shave = tid < 224;
    uint4 gv;
    auto stage_pre = [&](int t, int buf) {   // issue load + ugt LDS work
        int c0 = c0_of(t);
        if (shave)
            gv = *(const uint4*)(wsh + c0*32 + (size_t)srow * GT_K + scol*8);
        #pragma unroll
        for (int rep = 0; rep < 2; ++rep) {
            int j = tid + rep*256;
            int n = j >> 3, s = j & 7;
            unsigned short ix = s_idx[c0 + s];
            float u  = (float)s_uv[n][ix & 255];
            float gg = (float)s_uv[n][192 + (ix >> 8)];
            s_ugt[buf][n][s] = (f16)(u * gg);
        }
    };
    auto stage_post = [&](int buf) {         // vmcnt wait + LDS write land here
        if (shave) *(uint4*)&s_g[buf][srow][scol*8] = gv;
    };

    f32x4 acc = {0.f, 0.f, 0.f, 0.f};
    auto compute = [&](int buf, bool isA) {
        const f16x8 ug8 = *(const f16x8*)&s_ugt[buf][w*16 + lm][0];  // 1 b128 read
        #pragma unroll
        for (int s = 0; s < 8; ++s) {
            f16x8 a = *(const f16x8*)&s_g[buf][ra][s*32 + lq*8];
            f16 ug  = ug8[s];
            f16x8 vv = isA ? ((s & 1) ? vA1 : vA0) : vB;
            f16x8 b;
            #pragma unroll
            for (int j2 = 0; j2 < 8; ++j2) b[j2] = vv[j2] * ug;
            acc = __builtin_amdgcn_mfma_f32_16x16x32_f16(a, b, acc, 0, 0, 0);
        }
    };

    stage_pre(0, 0); stage_post(0);
    __syncthreads();
    for (int t = 0; t < 11; ++t) {
        int buf = t & 1;
        if (t < 10) stage_pre(t + 1, buf ^ 1);
        compute(buf, t < 5);
        if (t < 10) stage_post(buf ^ 1);
        __syncthreads();
    }

    // ---- epilogue: D col=lane&15 (node), row=lq*4+reg (out-k) ----
    int node = g*64 + w*16 + lm;
    if (lq == 0) {
        #pragma unroll
        for (int r = 0; r < 4; ++r) atomicAdd(&out[node*7 + r], acc[r]);
    } else if (lq == 1) {
        #pragma unroll
        for (int r = 0; r < 3; ++r) atomicAdd(&out[node*7 + 4 + r], acc[r]);
    }
}

// ---------------------------------------------------------------------------
// Fused cooperative kernel: 512 blocks x 256 threads, 2 blocks/CU co-resident
// (39552 B LDS, launch_bounds caps VGPR for 2 waves/EU).
// Phase A: G_T 44 k/block (512*44 = 22528) + node features 8/block.
// grid.sync() (device-scope fenced) then Phase B = main matmul.
// ---------------------------------------------------------------------------
__global__ __launch_bounds__(256, 2) void fused_kernel(
    const float* __restrict__ pos,
    const float* __restrict__ W1_0, const float* __restrict__ W1_1,
    const float* __restrict__ W2_0, const float* __restrict__ W2_1,
    const float* __restrict__ W3_0, const float* __restrict__ W3_1,
    const float* __restrict__ W3_2, const float* __restrict__ Wout,
    const float* __restrict__ bout,
    f16* __restrict__ wsh, float* __restrict__ out, int N)
{
    __shared__ __align__(16) char smem_raw[39552];
    (void)N;

    build_gt(W3_0, W3_1, W3_2, Wout, wsh, (float*)smem_raw, blockIdx.x * 44, 44);
    build_nodes(pos, W1_0, W1_1, W2_0, W2_1, bout, wsh, out,
                (float*)smem_raw, blockIdx.x * 8);

    __threadfence();                 // release ws writes to device scope
    cg::this_grid().sync();          // exec barrier + acquire

    phaseB(wsh, out, smem_raw, blockIdx.x >> 3, blockIdx.x & 7);
}

// ---------------- legacy 2-kernel fallback (same math, same micro-opts) ----
__global__ __launch_bounds__(256) void prep_kernel(
    const float* __restrict__ pos,
    const float* __restrict__ W1_0, const float* __restrict__ W1_1,
    const float* __restrict__ W2_0, const float* __restrict__ W2_1,
    const float* __restrict__ W3_0, const float* __restrict__ W3_1,
    const float* __restrict__ W3_2, const float* __restrict__ Wout,
    const float* __restrict__ bout,
    f16* __restrict__ wsh, float* __restrict__ out, int N)
{
    __shared__ __align__(16) float smem[3728];
    (void)N;
    if (blockIdx.x < 352)
        build_gt(W3_0, W3_1, W3_2, Wout, wsh, smem, blockIdx.x * 64, 64);
    else
        build_nodes(pos, W1_0, W1_1, W2_0, W2_1, bout, wsh, out, smem,
                    (blockIdx.x - 352) * 8);
}

__global__ __launch_bounds__(256) void main_kernel(
    const f16* __restrict__ wsh, float* __restrict__ out, int N)
{
    __shared__ __align__(16) char smem_raw[39552];
    (void)N;
    phaseB(wsh, out, smem_raw, blockIdx.x >> 3, blockIdx.x & 7);
}

extern "C" void kernel_launch(void* const* d_in, const int* in_sizes, int n_in,
                              void* d_out, int out_size, void* d_ws, size_t ws_size,
                              hipStream_t stream)
{
    const float* pos  = (const float*)d_in[0];
    const float* W1_0 = (const float*)d_in[1];
    const float* W1_1 = (const float*)d_in[2];
    const float* W2_0 = (const float*)d_in[3];
    const float* W2_1 = (const float*)d_in[4];
    const float* W3_0 = (const float*)d_in[5];
    const float* W3_1 = (const float*)d_in[6];
    const float* W3_2 = (const float*)d_in[7];
    const float* Wout = (const float*)d_in[8];
    const float* bout = (const float*)d_in[9];
    f16*   wsh = (f16*)d_ws;
    float* op  = (float*)d_out;
    int N = in_sizes[0] / 3;   // 4096

    void* args[] = { (void*)&pos, (void*)&W1_0, (void*)&W1_1, (void*)&W2_0,
                     (void*)&W2_1, (void*)&W3_0, (void*)&W3_1, (void*)&W3_2,
                     (void*)&Wout, (void*)&bout, (void*)&wsh, (void*)&op,
                     (void*)&N };
    hipError_t e = hipLaunchCooperativeKernel((void*)fused_kernel,
                                              dim3(512), dim3(256),
                                              args, 0, stream);
    if (e != hipSuccess) {
        // cooperative launch unavailable (e.g. under capture) — legacy path
        (void)hipGetLastError();
        prep_kernel<<<352 + N/8, 256, 0, stream>>>(pos, W1_0, W1_1, W2_0, W2_1,
                                                   W3_0, W3_1, W3_2, Wout, bout,
                                                   wsh, op, N);
        main_kernel<<<512, 256, 0, stream>>>(wsh, op, N);
    }
}

// Round 2
// 104.803 us; speedup vs baseline: 1.7177x; 1.7177x over previous
//
#include <hip/hip_runtime.h>
#include <math.h>

#define NS2 0.70710678118654752440f  // 1/sqrt(2)
#define NS3 0.57735026918962576451f  // 1/sqrt(3)
#define NS6 0.40824829046386301636f  // 1/sqrt(6)

typedef _Float16 f16;
typedef _Float16 f16x8 __attribute__((ext_vector_type(8)));
typedef float    f32x4 __attribute__((ext_vector_type(4)));

#define GT_K    22528
#define UV_ROW  216
#define OFF_UV  157696   // 7*22528

// ---------------------------------------------------------------------------
// G_T build: 4 o-split threads per k (q = tid>>6), kl = tid&63, k = k_base+kl
// for kl < n_k. LDS: s_wo[1680] + s_red[4][64][8].
// ---------------------------------------------------------------------------
__device__ __forceinline__ void build_gt(
    const float* __restrict__ W3_0, const float* __restrict__ W3_1,
    const float* __restrict__ W3_2, const float* __restrict__ Wout,
    f16* __restrict__ wsh, float* smem, int k_base, int n_k)
{
    const int tid = threadIdx.x;
    float* s_wo  = smem;            // Wout 240x7
    float* s_red = smem + 1680;     // [4][64][8] partials
    for (int i = tid; i < 1680; i += 256) s_wo[i] = Wout[i];
    __syncthreads();
    const int kl = tid & 63, q = tid >> 6;
    if (kl < n_k) {
        const int k = k_base + kl;
        float acc[7] = {0.f,0.f,0.f,0.f,0.f,0.f,0.f};
        if (k < 4096) {                            // P1  (L=64, quarter=16)
            const float* wr = W3_0 + (size_t)k * 64;
            #pragma unroll
            for (int oo = 0; oo < 16; oo += 4) {
                int o = q*16 + oo;
                float4 wv = *(const float4*)(wr + o);
                const float* w0 = s_wo + o * 7;
                #pragma unroll
                for (int kk = 0; kk < 7; ++kk)
                    acc[kk] = fmaf(wv.x, w0[kk], fmaf(wv.y, w0[7+kk],
                              fmaf(wv.z, w0[14+kk], fmaf(wv.w, w0[21+kk], acc[kk]))));
            }
        } else if (k < 10240) {                    // P4  (L=32, quarter=8)
            int it = k >> 6, s = it - 64, m = s >> 5, a2 = s & 31, l = k & 63;
            const float* wr = W3_1 + (size_t)(2048 + a2*64 + l) * 32;
            #pragma unroll
            for (int oo = 0; oo < 8; oo += 4) {
                int o = q*8 + oo;
                float4 wv = *(const float4*)(wr + o);
                const float* w0 = s_wo + (64 + o*3 + m) * 7;
                #pragma unroll
                for (int kk = 0; kk < 7; ++kk)
                    acc[kk] = fmaf(wv.x, w0[kk], fmaf(wv.y, w0[21+kk],
                              fmaf(wv.z, w0[42+kk], fmaf(wv.w, w0[63+kk], acc[kk]))));
            }
        } else {
            int it2 = (k - 10240) >> 5, l32 = k & 31;
            if (it2 < 32) {                        // P2  (L=64)
                const float* wr = W3_0 + (size_t)(4096 + it2*32 + l32) * 64;
                #pragma unroll
                for (int oo = 0; oo < 16; oo += 4) {
                    int o = q*16 + oo;
                    float4 wv = *(const float4*)(wr + o);
                    const float* w0 = s_wo + o * 7;
                    #pragma unroll
                    for (int kk = 0; kk < 7; ++kk)
                        acc[kk] = fmaf(wv.x, w0[kk], fmaf(wv.y, w0[7+kk],
                                  fmaf(wv.z, w0[14+kk], fmaf(wv.w, w0[21+kk], acc[kk]))));
                }
            } else if (it2 < 224) {                // P3  (L=32)
                int t = it2 - 32, m = t >> 6, a = t & 63;
                const float* wr = W3_1 + (size_t)(a*32 + l32) * 32;
                #pragma unroll
                for (int oo = 0; oo < 8; oo += 4) {
                    int o = q*8 + oo;
                    float4 wv = *(const float4*)(wr + o);
                    const float* w0 = s_wo + (64 + o*3 + m) * 7;
                    #pragma unroll
                    for (int kk = 0; kk < 7; ++kk)
                        acc[kk] = fmaf(wv.x, w0[kk], fmaf(wv.y, w0[21+kk],
                                  fmaf(wv.z, w0[42+kk], fmaf(wv.w, w0[63+kk], acc[kk]))));
                }
            } else {                               // P5  (L=16, quarter=4)
                int t = it2 - 224, m = t >> 5, a = t & 31;
                const float* wr = W3_2 + (size_t)(a*32 + l32) * 16;
                int o = q*4;
                float4 wv = *(const float4*)(wr + o);
                const float* w0 = s_wo + (160 + o*5 + m) * 7;
                #pragma unroll
                for (int kk = 0; kk < 7; ++kk)
                    acc[kk] = fmaf(wv.x, w0[kk], fmaf(wv.y, w0[35+kk],
                              fmaf(wv.z, w0[70+kk], fmaf(wv.w, w0[105+kk], acc[kk]))));
            }
        }
        #pragma unroll
        for (int r = 0; r < 7; ++r) s_red[(q*64 + kl)*8 + r] = acc[r];
    }
    __syncthreads();
    if (tid < n_k) {
        #pragma unroll
        for (int r = 0; r < 7; ++r) {
            float v = s_red[(      tid)*8 + r] + s_red[( 64 + tid)*8 + r]
                    + s_red[(128 + tid)*8 + r] + s_red[(192 + tid)*8 + r];
            wsh[(size_t)r * GT_K + k_base + tid] = (f16)v;
        }
    }
}

// ---------------------------------------------------------------------------
// Per-node features for 8 nodes starting at `base`. Overlays build_gt's s_wo
// region (safe: s_wo last read before build_gt's 2nd barrier; s_red disjoint).
// ---------------------------------------------------------------------------
__device__ __forceinline__ void build_nodes(
    const float* __restrict__ pos,
    const float* __restrict__ W1_0, const float* __restrict__ W1_1,
    const float* __restrict__ W2_0, const float* __restrict__ W2_1,
    const float* __restrict__ bout,
    f16* __restrict__ wsh, float* __restrict__ out, float* smem, int base)
{
    const int tid = threadIdx.x;
    float* s_f0 = smem;          // [8][64]
    float* s_f1 = smem + 512;    // [8][32]
    f16* uv = wsh + OFF_UV;
    {
        int d = tid & 63;
        #pragma unroll
        for (int jj = 0; jj < 2; ++jj) {
            int j = (tid >> 6) + jj * 4;
            int n = base + j;
            float px = pos[n*3+0], py = pos[n*3+1], pz = pos[n*3+2];
            float r  = sqrtf(px*px + py*py + pz*pz) + 1e-9f;
            float t0 = r - (5.0f/63.0f) * (float)d;
            s_f0[j*64 + d] = __expf(-4.f * t0 * t0);
        }
        {
            int j = tid >> 5, d1 = tid & 31;
            int n = base + j;
            float px = pos[n*3+0], py = pos[n*3+1], pz = pos[n*3+2];
            float r  = sqrtf(px*px + py*py + pz*pz) + 1e-9f;
            float t1 = r - (5.0f/31.0f) * (float)d1;
            s_f1[j*32 + d1] = __expf(-4.f * t1 * t1);
        }
        if (tid < 8) {
            int n = base + tid;
            float px = pos[n*3+0], py = pos[n*3+1], pz = pos[n*3+2];
            float r  = sqrtf(px*px + py*py + pz*pz) + 1e-9f;
            float iv = 1.0f / r;
            float d0 = py*iv, d1 = pz*iv, d2 = px*iv;       // (y,z,x)
            f16* row = uv + (size_t)n * UV_ROW;
            row[192+0] = (f16)d0;
            row[192+1] = (f16)d1;
            row[192+2] = (f16)d2;
            row[192+3] = (f16)(NS3 * (d0*d0 + d1*d1 + d2*d2));
            row[192+4] = (f16)(2.f*NS2*d2*d0);
            row[192+5] = (f16)(2.f*NS2*d0*d1);
            row[192+6] = (f16)(NS6*(2.f*d1*d1 - d2*d2 - d0*d0));
            row[192+7] = (f16)(2.f*NS2*d2*d1);
            row[192+8] = (f16)(NS2*(d2*d2 - d0*d0));
            row[201]   = (f16)1.0f;
        }
        if (tid < 56) out[base*7 + tid] = bout[tid % 7];
    }
    __syncthreads();
    {
        int c = tid & 63, jb = tid >> 6;
        float aa0 = 0.f, aa1 = 0.f, ba0 = 0.f, ba1 = 0.f;
        const float* wa = W1_0 + c;
        const float* wb = W2_0 + c;
        #pragma unroll 4
        for (int d = 0; d < 64; ++d) {
            float wav = wa[d*64], wbv = wb[d*64];
            float fA = s_f0[jb*64 + d], fB = s_f0[(jb+4)*64 + d];
            aa0 = fmaf(fA, wav, aa0);  aa1 = fmaf(fB, wav, aa1);
            ba0 = fmaf(fA, wbv, ba0);  ba1 = fmaf(fB, wbv, ba1);
        }
        uv[(size_t)(base+jb  )*UV_ROW +      c] = (f16)aa0;
        uv[(size_t)(base+jb+4)*UV_ROW +      c] = (f16)aa1;
        uv[(size_t)(base+jb  )*UV_ROW + 96 + c] = (f16)ba0;
        uv[(size_t)(base+jb+4)*UV_ROW + 96 + c] = (f16)ba1;

        int c1 = tid & 31, j8 = tid >> 5;
        float aA = 0.f, aB = 0.f;
        const float* wA = W1_1 + c1;
        const float* wB = W2_1 + c1;
        #pragma unroll 4
        for (int d = 0; d < 32; ++d) {
            float f = s_f1[j8*32 + d];
            aA = fmaf(f, wA[d*32], aA);
            aB = fmaf(f, wB[d*32], aB);
        }
        uv[(size_t)(base+j8)*UV_ROW +  64 + c1] = (f16)aA;
        uv[(size_t)(base+j8)*UV_ROW + 160 + c1] = (f16)aB;
    }
}

// prep: 512 blocks, each = 44 G_T columns + 8 nodes (one block-round, no tail)
__global__ __launch_bounds__(256) void prep_kernel(
    const float* __restrict__ pos,
    const float* __restrict__ W1_0, const float* __restrict__ W1_1,
    const float* __restrict__ W2_0, const float* __restrict__ W2_1,
    const float* __restrict__ W3_0, const float* __restrict__ W3_1,
    const float* __restrict__ W3_2, const float* __restrict__ Wout,
    const float* __restrict__ bout,
    f16* __restrict__ wsh, float* __restrict__ out, int N)
{
    __shared__ __align__(16) float smem[3728];
    (void)N;
    build_gt(W3_0, W3_1, W3_2, Wout, wsh, smem, blockIdx.x * 44, 44);
    build_nodes(pos, W1_0, W1_1, W2_0, W2_1, bout, wsh, out, smem,
                blockIdx.x * 8);
}

// ---------------------------------------------------------------------------
// main: grid 512 = (g = bi>>3 : 64-node group, kq = bi&7 : K-eighth).
// Whole k-eighth staged to LDS once; 88 MFMAs per wave with NO barriers in
// the compute loop (2 barriers total). A rows 7..15 are duplicates via
// ra = lm%7 — their D rows are discarded, so no zero row needed.
// LDS (79248 B, 2 blocks/CU):
//   [0]      s_g  [7][2832] f16  39648 B  (row stride 2832 -> rows 8 banks
//            apart; a-read = 2-way bank alias = free)
//   [39648]  s_uv [64][216] f16  27648 B
//   [67296]  s_ugt[64][92]  f16  11776 B  (stride 92 -> 16 distinct banks)
//   [79072]  s_idx[88]      u16    176 B
// ---------------------------------------------------------------------------
__global__ __launch_bounds__(256) void main_kernel(
    const f16* __restrict__ wsh, float* __restrict__ out, int N)
{
    __shared__ __align__(16) char smem[79248];
    f16* s_g   = (f16*)smem;                       // [7][2832]
    f16* s_uv  = (f16*)(smem + 39648);             // [64][216]
    f16* s_ugt = (f16*)(smem + 67296);             // [64][92]
    unsigned short* s_idx = (unsigned short*)(smem + 79072);
    (void)N;

    const int tid  = threadIdx.x;
    const int w    = tid >> 6;
    const int lane = tid & 63;
    const int lq   = lane >> 4;            // A/B k-subrange, D row-group
    const int lm   = lane & 15;            // A row (out-k) / B col (node)
    const int ra   = lm % 7;               // rows 7..15 duplicate 0..6 (discarded)
    const int g    = blockIdx.x >> 3;
    const int kq   = blockIdx.x & 7;

    // ---- two-phase staging: issue ALL global loads, then LDS writes ----
    uint4 ru[7];
    {
        const uint4* src = (const uint4*)(wsh + OFF_UV + (size_t)g * 64 * UV_ROW);
        #pragma unroll
        for (int it = 0; it < 7; ++it) {
            int j = tid + it*256;
            if (j < 1728) ru[it] = src[j];
        }
    }
    uint4 rg[10];
    #pragma unroll
    for (int it = 0; it < 10; ++it) {
        int j = tid + it*256;
        if (j < 2464) {
            int row = j / 352, col = j - row*352;
            size_t off = (size_t)row * GT_K +
                         (col < 160 ? kq*1280 + col*8
                                    : 10240 + kq*1536 + (col-160)*8);
            rg[it] = *(const uint4*)(wsh + off);
        }
    }
    if (tid < 88) {                         // local chunk -> (uidx, gidx)
        int c  = tid;
        int gc = (c < 40) ? (kq*40 + c) : (320 + kq*48 + (c - 40));
        int uidx, gidx;
        if (gc < 320) {
            int it = gc >> 1;
            if (it < 64) { uidx = it; gidx = 9; }
            else { int s = it - 64; uidx = 64 + (s & 31); gidx = s >> 5; }
        } else {
            int it2 = gc - 320;
            if (it2 < 32)       { uidx = 64 + it2;                  gidx = 3; }
            else if (it2 < 224) { int t = it2 - 32;  uidx = t & 63;         gidx = t >> 6; }
            else                { int t = it2 - 224; uidx = 64 + (t & 31);  gidx = 4 + (t >> 5); }
        }
        s_idx[c] = (unsigned short)(uidx | (gidx << 8));
    }
    {
        uint4* dst = (uint4*)s_uv;
        #pragma unroll
        for (int it = 0; it < 7; ++it) {
            int j = tid + it*256;
            if (j < 1728) dst[j] = ru[it];
        }
    }
    #pragma unroll
    for (int it = 0; it < 10; ++it) {
        int j = tid + it*256;
        if (j < 2464) {
            int row = j / 352, col = j - row*352;
            *(uint4*)(s_g + row*2832 + col*8) = rg[it];
        }
    }
    __syncthreads();

    // ---- ugt for all 88 chunks x 64 nodes (22 entries/thread) ----
    #pragma unroll
    for (int it = 0; it < 22; ++it) {
        int j = tid + it*256;               // 22*256 = 5632 exactly
        int n = j / 88, c = j - n*88;
        unsigned short ix = s_idx[c];
        float u  = (float)s_uv[n*UV_ROW + (ix & 255)];
        float gg = (float)s_uv[n*UV_ROW + 192 + (ix >> 8)];
        s_ugt[n*92 + c] = (f16)(u * gg);
    }
    const f16* myrow = s_uv + (w*16 + lm) * UV_ROW;
    f16x8 vA0 = *(const f16x8*)(myrow +  96 + lq*8);   // b0[ 0..31] slice
    f16x8 vA1 = *(const f16x8*)(myrow + 128 + lq*8);   // b0[32..63] slice
    f16x8 vB  = *(const f16x8*)(myrow + 160 + lq*8);   // B1[ 0..31] slice
    __syncthreads();

    // ---- barrier-free MFMA sweep over all 88 chunks ----
    f32x4 acc0 = {0.f,0.f,0.f,0.f}, acc1 = {0.f,0.f,0.f,0.f};
    const f16* arow  = s_g + ra*2832 + lq*8;
    const f16* ugrow = s_ugt + (w*16 + lm)*92;
    #pragma unroll
    for (int cb = 0; cb < 5; ++cb) {                   // A section: chunks 0..39
        f16x8 ug8 = *(const f16x8*)(ugrow + cb*8);
        #pragma unroll
        for (int s = 0; s < 8; ++s) {
            int c = cb*8 + s;
            f16x8 a  = *(const f16x8*)(arow + c*32);
            f16x8 vv = (s & 1) ? vA1 : vA0;            // chunk parity == s parity
            f16 ug   = ug8[s];
            f16x8 b;
            #pragma unroll
            for (int j2 = 0; j2 < 8; ++j2) b[j2] = vv[j2] * ug;
            if (s & 1) acc1 = __builtin_amdgcn_mfma_f32_16x16x32_f16(a, b, acc1, 0, 0, 0);
            else       acc0 = __builtin_amdgcn_mfma_f32_16x16x32_f16(a, b, acc0, 0, 0, 0);
        }
    }
    #pragma unroll
    for (int cb = 5; cb < 11; ++cb) {                  // B section: chunks 40..87
        f16x8 ug8 = *(const f16x8*)(ugrow + cb*8);
        #pragma unroll
        for (int s = 0; s < 8; ++s) {
            int c = cb*8 + s;
            f16x8 a  = *(const f16x8*)(arow + c*32);
            f16 ug   = ug8[s];
            f16x8 b;
            #pragma unroll
            for (int j2 = 0; j2 < 8; ++j2) b[j2] = vB[j2] * ug;
            if (s & 1) acc1 = __builtin_amdgcn_mfma_f32_16x16x32_f16(a, b, acc1, 0, 0, 0);
            else       acc0 = __builtin_amdgcn_mfma_f32_16x16x32_f16(a, b, acc0, 0, 0, 0);
        }
    }

    // ---- epilogue: D col=lm (node), row=lq*4+reg (out-k); rows 7..15 junk ----
    int node = g*64 + w*16 + lm;
    if (lq == 0) {
        #pragma unroll
        for (int r = 0; r < 4; ++r) atomicAdd(&out[node*7 + r], acc0[r] + acc1[r]);
    } else if (lq == 1) {
        #pragma unroll
        for (int r = 0; r < 3; ++r) atomicAdd(&out[node*7 + 4 + r], acc0[r] + acc1[r]);
    }
}

extern "C" void kernel_launch(void* const* d_in, const int* in_sizes, int n_in,
                              void* d_out, int out_size, void* d_ws, size_t ws_size,
                              hipStream_t stream)
{
    const float* pos  = (const float*)d_in[0];
    const float* W1_0 = (const float*)d_in[1];
    const float* W1_1 = (const float*)d_in[2];
    const float* W2_0 = (const float*)d_in[3];
    const float* W2_1 = (const float*)d_in[4];
    const float* W3_0 = (const float*)d_in[5];
    const float* W3_1 = (const float*)d_in[6];
    const float* W3_2 = (const float*)d_in[7];
    const float* Wout = (const float*)d_in[8];
    const float* bout = (const float*)d_in[9];
    f16*   wsh = (f16*)d_ws;
    float* op  = (float*)d_out;
    int N = in_sizes[0] / 3;   // 4096

    prep_kernel<<<512, 256, 0, stream>>>(pos, W1_0, W1_1, W2_0, W2_1,
                                         W3_0, W3_1, W3_2, Wout, bout, wsh, op, N);
    main_kernel<<<512, 256, 0, stream>>>(wsh, op, N);
}